// Round 13
// baseline (97.160 us; speedup 1.0000x reference)
//
#include <hip/hip_runtime.h>
#include <hip/hip_bf16.h>

// out[i] = x_i @ Q @ x_i, x [1024,2048] fp32 binary, Q [2048,2048] fp32.
// Identity: x^T Q x == x^T Q^T x -> MFMA B-operand (N x K) = row-major Q.
// Round 13: m-dimension collapsed into an in-kernel loop. Grid = 16 n-blocks
// x 16 k-splits = 256 blocks = 1 block/CU; each block stages its B tile ONCE
// (Q read exactly once chip-wide = HBM floor) and loops 8 m-slices with
// register-expanded A bits (R12-verified). Q staged fp32->cvt->swizzled
// ds_write IN-KERNEL (no bf16 prep round-trip — Q has zero reuse now);
// prep = x bit-pack only. Masks for all 1024 rows (16 KB) staged in the same
// single barrier window. Partials + reduce, no atomics, no fences.

#define B_ROWS 1024
#define N_BITS 2048

#define BM 128
#define BN 128
#define BK 128                   // = KPER
#define KSPLIT 16
#define KPER (N_BITS / KSPLIT)   // 128
#define NKB (N_BITS / BN)        // 16 n-blocks
#define NPART (NKB * KSPLIT)     // 256 partials per row
#define MSLICES (B_ROWS / BM)    // 8

typedef __bf16 bf16_t;
typedef __bf16 bf16x8 __attribute__((ext_vector_type(8)));
typedef float f32x4 __attribute__((ext_vector_type(4)));

__device__ __forceinline__ void load16_to_lds(const void* g, void* l) {
  __builtin_amdgcn_global_load_lds(
      (__attribute__((address_space(1))) void*)(g),
      (__attribute__((address_space(3))) void*)(l),
      16, 0, 0);
}

// 8 bits -> 8 bf16 {0.0, 1.0}; explicit selects, no scratch.
__device__ __forceinline__ bf16x8 expand8(unsigned int byte) {
  union { bf16x8 v; unsigned int w[4]; } u;
#pragma unroll
  for (int p = 0; p < 4; ++p) {
    const unsigned int lo = (byte & (1u << (2 * p)))     ? 0x00003F80u : 0u;
    const unsigned int hi = (byte & (1u << (2 * p + 1))) ? 0x3F800000u : 0u;
    u.w[p] = lo | hi;
  }
  return u.v;
}

// prep: pack x bits only (1 byte per 8 elems), fully coalesced.
__global__ __launch_bounds__(256) void prep_kernel(
    const float* __restrict__ x, unsigned char* __restrict__ xpack) {
  const int tid = blockIdx.x * 256 + threadIdx.x;
  const float4* s = (const float4*)(x + (size_t)tid * 8);
  float4 v0 = s[0];
  float4 v1 = s[1];
  unsigned int b = 0;
  b |= (v0.x != 0.f) << 0;
  b |= (v0.y != 0.f) << 1;
  b |= (v0.z != 0.f) << 2;
  b |= (v0.w != 0.f) << 3;
  b |= (v1.x != 0.f) << 4;
  b |= (v1.y != 0.f) << 5;
  b |= (v1.z != 0.f) << 6;
  b |= (v1.w != 0.f) << 7;
  xpack[tid] = (unsigned char)b;
}

// One block per (n-block, k-split): stage B fp32->bf16 + all masks once,
// then loop 8 m-slices of 64 MFMAs each. 16x16x32 frags (R12 engine).
__global__ __launch_bounds__(256, 1) void qubo_kernel(
    const float* __restrict__ Qf, const unsigned char* __restrict__ xpack,
    float* __restrict__ partial) {
  __shared__ bf16_t ldsB[BN * BK];                  // 32 KB
  __shared__ unsigned long long mAll[B_ROWS * 2];   // 16 KB: 128 n-bits/row

  const int tid  = threadIdx.x;
  const int lane = tid & 63;
  const int wave = tid >> 6;
  const int lrow = lane & 15;
  const int quad = lane >> 4;

  const int n0    = blockIdx.x * BN;
  const int kbase = blockIdx.y * KPER;
  const int nkid  = blockIdx.x * KSPLIT + blockIdx.y;  // 0..255

  // --- mask staging: 1024 rows x 16 B via global_load_lds (dest linear in
  // tid: p*4096 + tid*16), same single vmcnt window as B staging. ---
#pragma unroll
  for (int p = 0; p < 4; ++p) {
    const int r = p * 256 + tid;
    load16_to_lds(xpack + (size_t)r * (N_BITS / 8) + (n0 >> 3),
                  (void*)(mAll + r * 2));
  }

  // --- B staging: Q[n0:+128, kbase:+128] fp32 -> bf16 -> XOR-swizzled LDS.
  // Thread t: chunk c = t&15 (8 elems), rows (t>>4) + p*16. Global: 16 lanes
  // cover 512 B contiguous per row ✓. LDS slot = c ^ (row&15) -> frag
  // ds_read_b128 un-swizzles with ^lrow (row&15 == brow0, R12-verified). ---
  const int brow0 = tid >> 4;   // 0..15 == (row & 15) for all passes
  const int bc    = tid & 15;
  const int slot  = bc ^ brow0;
  float4 vb[8][2];
#pragma unroll
  for (int p = 0; p < 8; ++p) {
    const float4* g = (const float4*)(Qf + (size_t)(n0 + p * 16 + brow0) * N_BITS +
                                      kbase + bc * 8);
    vb[p][0] = g[0];
    vb[p][1] = g[1];
  }
#pragma unroll
  for (int p = 0; p < 8; ++p) {
    union { int4 i4; __hip_bfloat162 h2[4]; } u;
    u.h2[0] = __float22bfloat162_rn(make_float2(vb[p][0].x, vb[p][0].y));
    u.h2[1] = __float22bfloat162_rn(make_float2(vb[p][0].z, vb[p][0].w));
    u.h2[2] = __float22bfloat162_rn(make_float2(vb[p][1].x, vb[p][1].y));
    u.h2[3] = __float22bfloat162_rn(make_float2(vb[p][1].z, vb[p][1].w));
    *(int4*)&ldsB[(p * 16 + brow0) * BK + slot * 8] = u.i4;
  }

  // A bits for slice 0 (registers, no barrier dependency).
  unsigned long long aC[2][2], aN[2][2];
#pragma unroll
  for (int mi = 0; mi < 2; ++mi) {
    const unsigned long long* ap = (const unsigned long long*)(
        xpack + (size_t)(wave * 32 + mi * 16 + lrow) * (N_BITS / 8) +
        (kbase >> 3));
    aC[mi][0] = ap[0];
    aC[mi][1] = ap[1];
  }

  __syncthreads();   // the ONLY barrier: drains mask vmcnt + B lgkm

  for (int s = 0; s < MSLICES; ++s) {
    const int ms = s * BM;
    // prefetch next slice's A bits under this slice's MFMAs
    if (s + 1 < MSLICES) {
#pragma unroll
      for (int mi = 0; mi < 2; ++mi) {
        const unsigned long long* ap = (const unsigned long long*)(
            xpack + (size_t)(ms + BM + wave * 32 + mi * 16 + lrow) *
                (N_BITS / 8) + (kbase >> 3));
        aN[mi][0] = ap[0];
        aN[mi][1] = ap[1];
      }
    }

    f32x4 acc[2][8];
#pragma unroll
    for (int i = 0; i < 2; ++i)
#pragma unroll
      for (int j = 0; j < 8; ++j) acc[i][j] = (f32x4){0.f, 0.f, 0.f, 0.f};

#pragma unroll
    for (int ks = 0; ks < 4; ++ks) {
      const int c  = ks * 4 + quad;     // k-chunk 0..15
      const int ch = (c ^ lrow) * 8;    // un-swizzle (B frag row&15 == lrow)
      bf16x8 b[8], a[2];
#pragma unroll
      for (int ni = 0; ni < 8; ++ni)
        b[ni] = *(const bf16x8*)&ldsB[(ni * 16 + lrow) * BK + ch];
#pragma unroll
      for (int mi = 0; mi < 2; ++mi) {
        const unsigned int byte =
            (unsigned int)((aC[mi][c >> 3] >> ((c & 7) * 8)) & 0xFFu);
        a[mi] = expand8(byte);
      }
#pragma unroll
      for (int mi = 0; mi < 2; ++mi)
#pragma unroll
        for (int ni = 0; ni < 8; ++ni)
          acc[mi][ni] = __builtin_amdgcn_mfma_f32_16x16x32_bf16(
              a[mi], b[ni], acc[mi][ni], 0, 0, 0);
    }

    // Epilogue (R11/R12-verified). C/D: col = lane&15, row = quad*4 + reg.
#pragma unroll
    for (int mi = 0; mi < 2; ++mi) {
#pragma unroll
      for (int r = 0; r < 4; ++r) {
        const int rloc = wave * 32 + mi * 16 + quad * 4 + r;
        const int arow = ms + rloc;
        const unsigned long long w0 = mAll[arow * 2];      // cols 0..63
        const unsigned long long w1 = mAll[arow * 2 + 1];  // cols 64..127
        float sacc = 0.f;
#pragma unroll
        for (int ni = 0; ni < 4; ++ni)
          sacc += ((w0 >> (ni * 16 + lrow)) & 1ull) ? acc[mi][ni][r] : 0.f;
#pragma unroll
        for (int ni = 4; ni < 8; ++ni)
          sacc += ((w1 >> ((ni - 4) * 16 + lrow)) & 1ull) ? acc[mi][ni][r] : 0.f;
#pragma unroll
        for (int off = 1; off < 16; off <<= 1)
          sacc += __shfl_xor(sacc, off, 64);
        if (lrow == 0)
          partial[(size_t)arow * NPART + nkid] = sacc;
      }
    }

#pragma unroll
    for (int mi = 0; mi < 2; ++mi) {
      aC[mi][0] = aN[mi][0];
      aC[mi][1] = aN[mi][1];
    }
  }
}

// reduce: out[row] = sum of 256 partials. One block per row, coalesced.
__global__ __launch_bounds__(256) void reduce_kernel(
    const float* __restrict__ partial, float* __restrict__ out) {
  const int row = blockIdx.x;
  const int tid = threadIdx.x;
  float v = partial[(size_t)row * NPART + tid];
#pragma unroll
  for (int off = 1; off < 64; off <<= 1)
    v += __shfl_xor(v, off, 64);
  __shared__ float wsum[4];
  if ((tid & 63) == 0) wsum[tid >> 6] = v;
  __syncthreads();
  if (tid == 0) out[row] = wsum[0] + wsum[1] + wsum[2] + wsum[3];
}

extern "C" void kernel_launch(void* const* d_in, const int* in_sizes, int n_in,
                              void* d_out, int out_size, void* d_ws, size_t ws_size,
                              hipStream_t stream) {
  const float* x = (const float*)d_in[0];
  const float* Q = (const float*)d_in[1];
  float* out = (float*)d_out;

  unsigned char* xpack = (unsigned char*)d_ws;                    // 256 KB @ 0
  float* partial = (float*)((char*)d_ws + ((size_t)1 << 20));     // 1 MB @ 1M

  // 262144 pack threads = 1024 blocks
  prep_kernel<<<1024, 256, 0, stream>>>(x, xpack);

  dim3 grid(NKB, KSPLIT);  // (16, 16) = 256 blocks = 1/CU
  qubo_kernel<<<grid, dim3(256), 0, stream>>>(Q, xpack, partial);

  reduce_kernel<<<B_ROWS, 256, 0, stream>>>(partial, out);
}

// Round 14
// 86.602 us; speedup vs baseline: 1.1219x; 1.1219x over previous
//
#include <hip/hip_runtime.h>
#include <hip/hip_bf16.h>

// out[i] = x_i @ Q @ x_i, x [1024,2048] fp32 binary, Q [2048,2048] fp32.
// Identity: x^T Q x == x^T Q^T x -> MFMA B-operand (N x K) = row-major Q.
// FINAL (= R12, the measured best at 89.4 us): A-operand (binary x) never
// materialized as bf16 — lanes load 16 B of bit-packed x and expand 8-bit
// chunks to bf16 {0,1} in registers (VALU pipe, concurrent with MFMA).
// BK=128: ONE staging window + ONE barrier per block; KSPLIT=16 keeps the
// empirically-required 2048 blocks (4+ resident/CU — every lower/higher
// block count regressed: R4/R5/R13 lower, R10 higher). Bit-packed x mask
// rides the same vmcnt window (R11). Contention-free partials + tiny reduce
// (atomics regressed in R1/R2; device-scope fences were 13x disaster in R8).

#define B_ROWS 1024
#define N_BITS 2048

#define BM 128
#define BN 128
#define BK 128                   // = KPER, single tile
#define KSPLIT 16
#define KPER (N_BITS / KSPLIT)   // 128
#define NKB (N_BITS / BN)        // 16 n-blocks
#define NPART (NKB * KSPLIT)     // 256 partials per row

typedef __bf16 bf16_t;
typedef __bf16 bf16x8 __attribute__((ext_vector_type(8)));
typedef float f32x4 __attribute__((ext_vector_type(4)));

__device__ __forceinline__ void load16_to_lds(const void* g, void* l) {
  __builtin_amdgcn_global_load_lds(
      (__attribute__((address_space(1))) void*)(g),
      (__attribute__((address_space(3))) void*)(l),
      16, 0, 0);
}

// 8 bits -> 8 bf16 {0.0, 1.0}; explicit per-bit selects (no dynamic local
// array indexing -> no scratch).
__device__ __forceinline__ bf16x8 expand8(unsigned int byte) {
  union { bf16x8 v; unsigned int w[4]; } u;
#pragma unroll
  for (int p = 0; p < 4; ++p) {
    const unsigned int lo = (byte & (1u << (2 * p)))     ? 0x00003F80u : 0u;
    const unsigned int hi = (byte & (1u << (2 * p + 1))) ? 0x3F800000u : 0u;
    u.w[p] = lo | hi;
  }
  return u.v;
}

// prep: fp32 -> bf16 for Q (4M elems) into ws; pack x bits (1 byte / 8 elems).
__global__ __launch_bounds__(256) void prep_kernel(
    const float* __restrict__ x, const float* __restrict__ Q,
    bf16_t* __restrict__ qb, unsigned char* __restrict__ xpack) {
  const int tid = blockIdx.x * 256 + threadIdx.x;
  const int PTH = (B_ROWS * N_BITS) / 8;  // 262144 pack threads
  if (tid < PTH) {
    const float4* s = (const float4*)(x + (size_t)tid * 8);
    float4 v0 = s[0];
    float4 v1 = s[1];
    unsigned int b = 0;
    b |= (v0.x != 0.f) << 0;
    b |= (v0.y != 0.f) << 1;
    b |= (v0.z != 0.f) << 2;
    b |= (v0.w != 0.f) << 3;
    b |= (v1.x != 0.f) << 4;
    b |= (v1.y != 0.f) << 5;
    b |= (v1.z != 0.f) << 6;
    b |= (v1.w != 0.f) << 7;
    xpack[tid] = (unsigned char)b;
  } else {
    const size_t o = (size_t)(tid - PTH) * 8;
    const float4* s = (const float4*)(Q + o);
    float4 v0 = s[0];
    float4 v1 = s[1];
    union { int4 i4; __hip_bfloat16 h[8]; } u;
    u.h[0] = __float2bfloat16(v0.x);
    u.h[1] = __float2bfloat16(v0.y);
    u.h[2] = __float2bfloat16(v0.z);
    u.h[3] = __float2bfloat16(v0.w);
    u.h[4] = __float2bfloat16(v1.x);
    u.h[5] = __float2bfloat16(v1.y);
    u.h[6] = __float2bfloat16(v1.z);
    u.h[7] = __float2bfloat16(v1.w);
    ((int4*)(qb + o))[0] = u.i4;
  }
}

// GEMM S = bits(X) @ Qb^T (16x16x32 frags) + bit-masked row-dot -> partials.
// 4 waves split M (32 rows x 128 cols each, acc 2x8). ONE barrier per block.
__global__ __launch_bounds__(256) void qubo_kernel(
    const bf16_t* __restrict__ Qb, const unsigned char* __restrict__ xpack,
    float* __restrict__ partial) {
  __shared__ bf16_t ldsB[BN * BK];             // 32 KB
  __shared__ unsigned long long mbits[BM * 2]; // 2 KB: 128 n-bits per row

  const int tid  = threadIdx.x;
  const int lane = tid & 63;
  const int wave = tid >> 6;     // 0..3 -> owns rows [wave*32, wave*32+32)
  const int lrow = lane & 15;
  const int quad = lane >> 4;

  const int m0    = blockIdx.y * BM;
  const int n0    = blockIdx.x * BN;
  const int kbase = blockIdx.z * KPER;
  const int nkid  = blockIdx.x * KSPLIT + blockIdx.z;  // 0..255

  // B staging: 128 rows x 16 chunks (16B) = 8 per thread. LDS dest linear in
  // tid (byte off = p*4096 + tid*16, wave-uniform base + lane*16 as
  // global_load_lds requires). GLOBAL chunk XOR-swizzled: LDS slot s of row r
  // holds global chunk s ^ (r&15) -> frag reads 2-way banked (free).
  const int srow = tid >> 4;        // 0..15
  const int slot = tid & 15;
  const int gch  = slot ^ srow;     // r&15 == srow for every pass
#pragma unroll
  for (int p = 0; p < 8; ++p) {
    const int r = p * 16 + srow;
    load16_to_lds(Qb + (size_t)(n0 + r) * N_BITS + kbase + gch * 8,
                  ldsB + r * BK + slot * 8);
  }
  // mask bits (n0-slice): 128 rows x 16 B by waves 0-1, same vmcnt window.
  if (wave < 2) {
    load16_to_lds(xpack + (size_t)(m0 + tid) * (N_BITS / 8) + (n0 >> 3),
                  (void*)(mbits + tid * 2));
  }

  // A bits (k-slice): 16 B per owned row, straight to registers — no barrier
  // dependency. 4 lanes/row redundancy is L1-broadcast.
  unsigned long long abits[2][2];
#pragma unroll
  for (int mi = 0; mi < 2; ++mi) {
    const int row = m0 + wave * 32 + mi * 16 + lrow;
    const unsigned long long* ap =
        (const unsigned long long*)(xpack + (size_t)row * (N_BITS / 8) +
                                    (kbase >> 3));
    abits[mi][0] = ap[0];
    abits[mi][1] = ap[1];
  }

  f32x4 acc[2][8];
#pragma unroll
  for (int i = 0; i < 2; ++i)
#pragma unroll
    for (int j = 0; j < 8; ++j) acc[i][j] = (f32x4){0.f, 0.f, 0.f, 0.f};

  __syncthreads();   // the ONLY barrier: drains B + mask staging

#pragma unroll
  for (int ks = 0; ks < 4; ++ks) {
    const int c  = ks * 4 + quad;        // chunk index 0..15 (k = c*8..c*8+7)
    const int ch = (c ^ lrow) * 8;       // un-swizzle (frag row & 15 == lrow)
    bf16x8 b[8], a[2];
#pragma unroll
    for (int ni = 0; ni < 8; ++ni)
      b[ni] = *(const bf16x8*)&ldsB[(ni * 16 + lrow) * BK + ch];
#pragma unroll
    for (int mi = 0; mi < 2; ++mi) {
      const unsigned int byte =
          (unsigned int)((abits[mi][c >> 3] >> ((c & 7) * 8)) & 0xFFu);
      a[mi] = expand8(byte);
    }
#pragma unroll
    for (int mi = 0; mi < 2; ++mi)
#pragma unroll
      for (int ni = 0; ni < 8; ++ni)
        acc[mi][ni] = __builtin_amdgcn_mfma_f32_16x16x32_bf16(
            a[mi], b[ni], acc[mi][ni], 0, 0, 0);
  }

  // Epilogue (R11-verified). 16x16 C/D: col = lane&15, row = quad*4 + reg.
  // Bit-mask from LDS (broadcast), cndmask-adds, 16-lane shuffle reduce, one
  // plain store per (row, nkid). No atomics, no fences.
#pragma unroll
  for (int mi = 0; mi < 2; ++mi) {
#pragma unroll
    for (int r = 0; r < 4; ++r) {
      const int rloc = wave * 32 + mi * 16 + quad * 4 + r;
      const unsigned long long w0 = mbits[rloc * 2];      // cols 0..63
      const unsigned long long w1 = mbits[rloc * 2 + 1];  // cols 64..127
      float s = 0.f;
#pragma unroll
      for (int ni = 0; ni < 4; ++ni)
        s += ((w0 >> (ni * 16 + lrow)) & 1ull) ? acc[mi][ni][r] : 0.f;
#pragma unroll
      for (int ni = 4; ni < 8; ++ni)
        s += ((w1 >> ((ni - 4) * 16 + lrow)) & 1ull) ? acc[mi][ni][r] : 0.f;
#pragma unroll
      for (int off = 1; off < 16; off <<= 1)
        s += __shfl_xor(s, off, 64);
      if (lrow == 0)
        partial[(size_t)(m0 + rloc) * NPART + nkid] = s;
    }
  }
}

// reduce: out[row] = sum of 256 partials. One block per row, coalesced.
__global__ __launch_bounds__(256) void reduce_kernel(
    const float* __restrict__ partial, float* __restrict__ out) {
  const int row = blockIdx.x;
  const int tid = threadIdx.x;
  float v = partial[(size_t)row * NPART + tid];
#pragma unroll
  for (int off = 1; off < 64; off <<= 1)
    v += __shfl_xor(v, off, 64);
  __shared__ float wsum[4];
  if ((tid & 63) == 0) wsum[tid >> 6] = v;
  __syncthreads();
  if (tid == 0) out[row] = wsum[0] + wsum[1] + wsum[2] + wsum[3];
}

extern "C" void kernel_launch(void* const* d_in, const int* in_sizes, int n_in,
                              void* d_out, int out_size, void* d_ws, size_t ws_size,
                              hipStream_t stream) {
  const float* x = (const float*)d_in[0];
  const float* Q = (const float*)d_in[1];
  float* out = (float*)d_out;

  bf16_t* qb = (bf16_t*)d_ws;                                                // 8 MB @ 0
  unsigned char* xpack = (unsigned char*)((char*)d_ws + ((size_t)8 << 20));  // 256 KB @ 8M
  float* partial = (float*)((char*)d_ws + ((size_t)9 << 20));                // 1 MB @ 9M

  // 262144 pack threads + 524288 Q threads = 786432 = 3072 blocks
  prep_kernel<<<3072, 256, 0, stream>>>(x, Q, qb, xpack);

  dim3 grid(NKB, B_ROWS / BM, KSPLIT);  // (16, 8, 16) = 2048 blocks
  qubo_kernel<<<grid, dim3(256), 0, stream>>>(qb, xpack, partial);

  reduce_kernel<<<B_ROWS, 256, 0, stream>>>(partial, out);
}